// Round 6
// baseline (925.021 us; speedup 1.0000x reference)
//
#include <hip/hip_runtime.h>
#include <math.h>

#define DD 32
#define DD4 128
#define TPB 256
#define TKTPB 1024
#define LDSCAP 6144

// ---------- sortable key mappings ----------
__device__ __forceinline__ unsigned long long dsort_key(double x) {
  unsigned long long b = (unsigned long long)__double_as_longlong(x);
  return (b & 0x8000000000000000ull) ? ~b : (b | 0x8000000000000000ull);
}
__device__ __forceinline__ double dunsort_key(unsigned long long k) {
  unsigned long long b = (k & 0x8000000000000000ull) ? (k ^ 0x8000000000000000ull) : ~k;
  return __longlong_as_double((long long)b);
}
__device__ __forceinline__ unsigned int fsort_key(float x) {
  unsigned int b = __float_as_uint(x);
  return (b & 0x80000000u) ? ~b : (b | 0x80000000u);
}
__device__ __forceinline__ float funsort_key(unsigned int k) {
  unsigned int b = (k & 0x80000000u) ? (k ^ 0x80000000u) : ~k;
  return __uint_as_float(b);
}

// ---------- K1: M = Wq^T Wk (f64) ----------
__global__ __launch_bounds__(TPB) void k_precompute_M(
    const float* __restrict__ Wq, const float* __restrict__ Wk,
    double* __restrict__ M64) {
  int t = blockIdx.x * blockDim.x + threadIdx.x;  // 16384 threads
  int i = t >> 7, j = t & 127;
  double acc = 0.0;
  for (int k = 0; k < DD4; ++k)
    acc += (double)Wq[k * DD4 + i] * (double)Wk[k * DD4 + j];
  M64[i * DD4 + j] = acc;
}

// ---------- K2: per-query precompute p (64), pD (32), c (scalar) ----------
__global__ __launch_bounds__(64) void k_per_query(
    const double* __restrict__ M64,
    const float* __restrict__ qemb, const float* __restrict__ remb,
    double* __restrict__ p64, double* __restrict__ pD64, double* __restrict__ c64,
    float* __restrict__ p32, float* __restrict__ pD32, float* __restrict__ c32) {
  int q = blockIdx.x;
  int l = threadIdx.x;  // 64 threads = 1 wave
  __shared__ double qr[64];
  qr[l] = (l < DD) ? (double)qemb[q * DD + l] : (double)remb[q * DD + (l - DD)];
  __syncthreads();
  double a = 0.0;
  for (int j = 0; j < 64; ++j) a += M64[l * DD4 + 64 + j] * qr[j];
  double ct = 0.0;
  for (int j = 0; j < 64; ++j) ct += M64[(64 + j) * DD4 + l] * qr[j];
  if (l >= DD) a += ct;  // fold rel-part of z^T C x into p (x==y there)
  p64[q * 64 + l] = a;
  p32[q * 64 + l] = (float)a;
  if (l < DD) {
    pD64[q * DD + l] = ct;
    pD32[q * DD + l] = (float)ct;
  }
  double a3 = 0.0;
  for (int j = 0; j < 64; ++j) a3 += M64[(64 + l) * DD4 + 64 + j] * qr[j];
  a3 *= qr[l];
  for (int o = 32; o; o >>= 1) a3 += __shfl_xor(a3, o);
  if (l == 0) { c64[q] = a3; c32[q] = (float)a3; }
}

// ---------- K3: per-node precompute t = G11 h, u = G12^T h, v = G21 h ----------
template <typename T>
__global__ __launch_bounds__(TPB) void k_node_pre(
    const double* __restrict__ M64, const float* __restrict__ repr,
    float* __restrict__ t, float* __restrict__ u, float* __restrict__ v, int N_) {
  __shared__ T G11s[32 * 32];
  __shared__ T G12Ts[32 * 32];
  __shared__ T G21s[32 * 32];
  for (int i = threadIdx.x; i < 1024; i += TPB) {
    int r = i >> 5, c = i & 31;
    G11s[i]  = (T)M64[r * DD4 + c];
    G12Ts[i] = (T)M64[c * DD4 + 32 + r];
    G21s[i]  = (T)M64[(32 + r) * DD4 + c];
  }
  __syncthreads();
  int n = blockIdx.x * TPB + threadIdx.x;
  if (n >= N_) return;
  float h[32];
  const float4* h4 = (const float4*)repr + (size_t)n * 8;
#pragma unroll
  for (int j = 0; j < 8; ++j) {
    float4 x = h4[j];
    h[4 * j] = x.x; h[4 * j + 1] = x.y; h[4 * j + 2] = x.z; h[4 * j + 3] = x.w;
  }
  float4* t4 = (float4*)t + (size_t)n * 8;
  float4* u4 = (float4*)u + (size_t)n * 8;
  float4* v4 = (float4*)v + (size_t)n * 8;
#pragma unroll
  for (int ig = 0; ig < 8; ++ig) {
    float to[4], uo[4], vo[4];
#pragma unroll
    for (int ii = 0; ii < 4; ++ii) {
      const int i = ig * 4 + ii;
      T at = (T)0, au = (T)0, av = (T)0;
#pragma unroll
      for (int j = 0; j < 32; ++j) {
        T hj = (T)h[j];
        at += G11s[i * 32 + j] * hj;
        au += G12Ts[i * 32 + j] * hj;
        av += G21s[i * 32 + j] * hj;
      }
      to[ii] = (float)at; uo[ii] = (float)au; vo[ii] = (float)av;
    }
    t4[ig] = make_float4(to[0], to[1], to[2], to[3]);
    u4[ig] = make_float4(uo[0], uo[1], uo[2], uo[3]);
    v4[ig] = make_float4(vo[0], vo[1], vo[2], vo[3]);
  }
}

// ---------- K4: thread-per-edge logits ----------
template <typename T>
__global__ __launch_bounds__(TPB) void k_edge_logits(
    const double* __restrict__ M64,
    const float* __restrict__ repr, const float* __restrict__ rel,
    const int* __restrict__ src, const int* __restrict__ dst, const int* __restrict__ eg,
    const float* __restrict__ tvec, const float* __restrict__ uvec, const float* __restrict__ vvec,
    const T* __restrict__ pq, const T* __restrict__ pDq, const T* __restrict__ cq,
    T* __restrict__ logits, void* __restrict__ mkey, int E) {
  __shared__ T G22s[32 * 32];
  for (int i = threadIdx.x; i < 1024; i += TPB) {
    int r = i >> 5, c = i & 31;
    G22s[i] = (T)M64[(32 + r) * DD4 + 32 + c];
  }
  __syncthreads();
  const int e = blockIdx.x * TPB + threadIdx.x;
  if (e >= E) return;
  const int s = src[e], d = dst[e], q = eg[e];
  T acc = cq[q];
  {
    float hs[32], td[32];
    const float4* a4 = (const float4*)repr + (size_t)s * 8;
    const float4* b4 = (const float4*)tvec + (size_t)d * 8;
#pragma unroll
    for (int j = 0; j < 8; ++j) {
      float4 x = a4[j], y = b4[j];
      hs[4 * j] = x.x; hs[4 * j + 1] = x.y; hs[4 * j + 2] = x.z; hs[4 * j + 3] = x.w;
      td[4 * j] = y.x; td[4 * j + 1] = y.y; td[4 * j + 2] = y.z; td[4 * j + 3] = y.w;
    }
#pragma unroll
    for (int i = 0; i < 32; ++i)
      acc += (T)hs[i] * ((T)td[i] + pq[q * 64 + i]);
  }
  {
    float hd[32];
    const float4* a4 = (const float4*)repr + (size_t)d * 8;
#pragma unroll
    for (int j = 0; j < 8; ++j) {
      float4 x = a4[j];
      hd[4 * j] = x.x; hd[4 * j + 1] = x.y; hd[4 * j + 2] = x.z; hd[4 * j + 3] = x.w;
    }
#pragma unroll
    for (int i = 0; i < 32; ++i)
      acc += (T)hd[i] * pDq[q * DD + i];
  }
  float rl[32];
  {
    const float4* r4 = (const float4*)rel + (size_t)e * 8;
#pragma unroll
    for (int j = 0; j < 8; ++j) {
      float4 x = r4[j];
      rl[4 * j] = x.x; rl[4 * j + 1] = x.y; rl[4 * j + 2] = x.z; rl[4 * j + 3] = x.w;
    }
  }
  T rowv[32];
  {
    const float4* u4 = (const float4*)uvec + (size_t)s * 8;
    const float4* v4 = (const float4*)vvec + (size_t)d * 8;
#pragma unroll
    for (int j = 0; j < 8; ++j) {
      float4 x = u4[j], y = v4[j];
      rowv[4 * j + 0] = (T)(x.x + y.x) + pq[q * 64 + 32 + 4 * j + 0];
      rowv[4 * j + 1] = (T)(x.y + y.y) + pq[q * 64 + 32 + 4 * j + 1];
      rowv[4 * j + 2] = (T)(x.z + y.z) + pq[q * 64 + 32 + 4 * j + 2];
      rowv[4 * j + 3] = (T)(x.w + y.w) + pq[q * 64 + 32 + 4 * j + 3];
    }
  }
#pragma unroll 4
  for (int j = 0; j < 32; ++j) {
    const T rj = (T)rl[j];
#pragma unroll
    for (int i = 0; i < 32; ++i)
      rowv[i] += G22s[i * 32 + j] * rj;
  }
#pragma unroll
  for (int i = 0; i < 32; ++i) acc += (T)rl[i] * rowv[i];

  logits[e] = acc;
  if constexpr (sizeof(T) == 8) {
    atomicMax((unsigned long long*)mkey + s, dsort_key((double)acc));
  } else {
    atomicMax((unsigned int*)mkey + s, fsort_key((float)acc));
  }
}

// ---------- K5: ex = exp(l - m[src]); s[src] += ex (in-place) ----------
__global__ __launch_bounds__(TPB) void k_expsum64(
    double* __restrict__ io, const unsigned long long* __restrict__ mkey,
    const int* __restrict__ src, double* __restrict__ ssum, int E) {
  int e = blockIdx.x * blockDim.x + threadIdx.x;
  if (e >= E) return;
  int s = src[e];
  double ex = exp(io[e] - dunsort_key(mkey[s]));
  io[e] = ex;
  atomicAdd(&ssum[s], ex);
}
__global__ __launch_bounds__(TPB) void k_expsum32(
    float* __restrict__ io, const unsigned int* __restrict__ mkey,
    const int* __restrict__ src, float* __restrict__ ssum, int E) {
  int e = blockIdx.x * blockDim.x + threadIdx.x;
  if (e >= E) return;
  int s = src[e];
  float ex = expf(io[e] - funsort_key(mkey[s]));
  io[e] = ex;
  atomicAdd(&ssum[s], ex);
}

// ---------- K6: w1 = ex/s; target key = fsort(f32(w1) * score[src]) ----------
__global__ __launch_bounds__(TPB) void k_weights_target(
    const double* __restrict__ ex, const double* __restrict__ ssum,
    const int* __restrict__ src, const float* __restrict__ score,
    float* __restrict__ w1f, unsigned int* __restrict__ tkey, int E) {
  int e = blockIdx.x * blockDim.x + threadIdx.x;
  if (e >= E) return;
  int s = src[e];
  double w = ex[e] / ssum[s];
  float wf = (float)w;
  w1f[e] = wf;
  float tgt = wf * score[s];
  tkey[e] = fsort_key(tgt);
}

// ---------- K7: per-query top-k, LDS-cached keys + binary search on u32 key space ----------
__device__ __forceinline__ int blockReduceSum16(int v, int* sm) {
  for (int o = 32; o; o >>= 1) v += __shfl_xor(v, o);
  int w = threadIdx.x >> 6;
  __syncthreads();
  if ((threadIdx.x & 63) == 0) sm[w] = v;
  __syncthreads();
  int t = 0;
#pragma unroll
  for (int i = 0; i < TKTPB / 64; ++i) t += sm[i];
  return t;
}

__global__ __launch_bounds__(TKTPB) void k_topk(
    const unsigned int* __restrict__ tkey, const float* __restrict__ w1f,
    const int* __restrict__ eg, const int* __restrict__ maxe,
    float* __restrict__ w1p, int E) {
  __shared__ unsigned int keys[LDSCAP];
  __shared__ int sm[TKTPB / 64];
  const int q = blockIdx.x;
  // lower_bound(q), lower_bound(q+1) over sorted eg
  int lo0 = 0, hi0 = E;
  while (lo0 < hi0) { int mid = (lo0 + hi0) >> 1; if (eg[mid] < q) lo0 = mid + 1; else hi0 = mid; }
  const int s = lo0;
  hi0 = E;
  while (lo0 < hi0) { int mid = (lo0 + hi0) >> 1; if (eg[mid] < q + 1) lo0 = mid + 1; else hi0 = mid; }
  const int e2 = lo0;
  const int n = e2 - s;
  const int K = maxe[0];
  if (n <= K) {
    for (int i = s + threadIdx.x; i < e2; i += TKTPB) w1p[i] = w1f[i];
    return;
  }
  const bool useLds = (n <= LDSCAP);
  if (useLds) {
    for (int i = threadIdx.x; i < n; i += TKTPB) keys[i] = tkey[s + i];
    __syncthreads();
  }
  // find kth-largest key: max x with count(key >= x) >= K
  unsigned int lo = 0u, hi = 0xFFFFFFFFu;
  while (lo < hi) {
    unsigned int mid = lo + ((hi - lo) >> 1) + 1u;
    int c = 0;
    if (useLds) {
      for (int i = threadIdx.x; i < n; i += TKTPB) c += (keys[i] >= mid) ? 1 : 0;
    } else {
      for (int i = s + threadIdx.x; i < e2; i += TKTPB) c += (tkey[i] >= mid) ? 1 : 0;
    }
    c = blockReduceSum16(c, sm);
    if (c >= K) lo = mid; else hi = mid - 1u;
  }
  const unsigned int kth = lo;
  int cgt = 0;
  if (useLds) {
    for (int i = threadIdx.x; i < n; i += TKTPB) cgt += (keys[i] > kth) ? 1 : 0;
  } else {
    for (int i = s + threadIdx.x; i < e2; i += TKTPB) cgt += (tkey[i] > kth) ? 1 : 0;
  }
  cgt = blockReduceSum16(cgt, sm);
  const int r = K - cgt;  // ties kept by ascending index (lexsort-stable)
  for (int i = threadIdx.x; i < n; i += TKTPB) {
    const unsigned int kk = useLds ? keys[i] : tkey[s + i];
    float v = 0.f;
    if (kk > kth) {
      v = w1f[s + i];
    } else if (kk == kth) {
      int pre = 0;
      if (useLds) {
        for (int j = 0; j < i; ++j) pre += (keys[j] == kth) ? 1 : 0;
      } else {
        for (int j = s; j < s + i; ++j) pre += (tkey[j] == kth) ? 1 : 0;
      }
      if (pre < r) v = w1f[s + i];
    }
    w1p[s + i] = v;
  }
}

// ---------- K8: layer-1 scatter: score + repr agg over kept edges (sparse) ----------
__global__ __launch_bounds__(TPB) void k_apply1(
    const float* __restrict__ w1p, const int* __restrict__ src, const int* __restrict__ dst,
    const float* __restrict__ repr0, const float* __restrict__ score,
    float* __restrict__ agg, float* __restrict__ score_out, int E) {
  int t = blockIdx.x * blockDim.x + threadIdx.x;
  int e = t >> 3, part = t & 7;
  if (e >= E) return;
  float w = w1p[e];
  if (w == 0.f) return;
  int sv = src[e], dv = dst[e];
  const float4 rv = ((const float4*)repr0)[sv * 8 + part];
  float* ap = agg + (size_t)dv * DD + part * 4;
  atomicAdd(ap + 0, w * rv.x);
  atomicAdd(ap + 1, w * rv.y);
  atomicAdd(ap + 2, w * rv.z);
  atomicAdd(ap + 3, w * rv.w);
  if (part == 0) atomicAdd(score_out + dv, w * score[sv]);
}

// ---------- K9: out = wa*a + wb*b ----------
__global__ __launch_bounds__(TPB) void k_mix(
    const float4* __restrict__ a, const float4* __restrict__ b,
    float4* __restrict__ out, float wa, float wb, int n4) {
  int i = blockIdx.x * blockDim.x + threadIdx.x;
  if (i >= n4) return;
  float4 x = a[i], y = b[i];
  out[i] = make_float4(wa * x.x + wb * y.x, wa * x.y + wb * y.y,
                       wa * x.z + wb * y.z, wa * x.w + wb * y.w);
}

// ---------- CSR build for layer-0 dst ----------
__global__ __launch_bounds__(TPB) void k_hist(
    const int* __restrict__ dst, int* __restrict__ cnt, int E) {
  int e = blockIdx.x * blockDim.x + threadIdx.x;
  if (e >= E) return;
  atomicAdd(&cnt[dst[e]], 1);
}

#define SCHUNK 1024
__global__ __launch_bounds__(TPB) void k_scan1(
    const int* __restrict__ cnt, int* __restrict__ off, int* __restrict__ bsum, int N_) {
  __shared__ int sd[TPB];
  const int b = blockIdx.x, t = threadIdx.x;
  const int base = b * SCHUNK + t * 4;
  int v[4];
  int s4 = 0;
#pragma unroll
  for (int k = 0; k < 4; ++k) {
    v[k] = (base + k < N_) ? cnt[base + k] : 0;
    s4 += v[k];
  }
  sd[t] = s4;
  __syncthreads();
  // Hillis-Steele inclusive scan
  for (int o = 1; o < TPB; o <<= 1) {
    int x = (t >= o) ? sd[t - o] : 0;
    __syncthreads();
    sd[t] += x;
    __syncthreads();
  }
  int excl = sd[t] - s4;
  if (t == TPB - 1) bsum[b] = sd[t];
  int run = excl;
#pragma unroll
  for (int k = 0; k < 4; ++k) {
    if (base + k < N_) { off[base + k] = run; run += v[k]; }
  }
}

__global__ void k_scan2(int* __restrict__ bsum, int* __restrict__ off, int nblk, int N_, int E) {
  if (threadIdx.x != 0 || blockIdx.x != 0) return;
  int run = 0;
  for (int i = 0; i < nblk; ++i) { int tmp = bsum[i]; bsum[i] = run; run += tmp; }
  off[N_] = E;
}

__global__ __launch_bounds__(TPB) void k_scan3(
    int* __restrict__ off, const int* __restrict__ bsum, int* __restrict__ cursor, int N_) {
  int i = blockIdx.x * blockDim.x + threadIdx.x;
  if (i >= N_) return;
  int v = off[i] + bsum[i >> 10];
  off[i] = v;
  cursor[i] = v;
}

// ---------- K12a: scatter packed {w, src} into dst-CSR order ----------
__global__ __launch_bounds__(TPB) void k_scatter0(
    const float* __restrict__ ex, const float* __restrict__ ssum,
    const int* __restrict__ src, const int* __restrict__ dst,
    int* __restrict__ cursor, float2* __restrict__ pk, int E) {
  int e = blockIdx.x * blockDim.x + threadIdx.x;
  if (e >= E) return;
  int s = src[e];
  float w = ex[e] / ssum[s];
  int pos = atomicAdd(&cursor[dst[e]], 1);
  pk[pos] = make_float2(w, __int_as_float(s));
}

// ---------- K12b: gather per dst node + fused mix + Linear + LeakyReLU ----------
__global__ __launch_bounds__(TPB) void k_gather_final(
    const float2* __restrict__ pk, const int* __restrict__ off,
    const float* __restrict__ repr1,
    const float* __restrict__ Wlin, const float* __restrict__ blin,
    float* __restrict__ out_repr, int N_) {
  __shared__ float WsT[DD * DD];   // WsT[j*32+i] = Wlin[i*32+j]
  __shared__ float bs[DD];
  for (int i = threadIdx.x; i < DD * DD; i += TPB) {
    int r = i >> 5, c = i & 31;
    WsT[c * DD + r] = Wlin[i];
  }
  if (threadIdx.x < DD) bs[threadIdx.x] = blin[threadIdx.x];
  __syncthreads();
  const int n = blockIdx.x * 8 + (threadIdx.x >> 5);  // node
  const int c = threadIdx.x & 31;                     // component
  if (n >= N_) return;
  float acc = 0.f;
  const int j1 = off[n + 1];
  for (int j = off[n]; j < j1; ++j) {
    float2 p = pk[j];
    int s = __float_as_int(p.y);
    acc += p.x * repr1[(size_t)s * DD + c];
  }
  float mix = 0.8f * acc + 0.2f * repr1[(size_t)n * DD + c];
  float o = bs[c];
#pragma unroll 8
  for (int j = 0; j < DD; ++j) {
    float mj = __shfl(mix, j, 32);
    o += WsT[j * DD + c] * mj;
  }
  out_repr[(size_t)n * DD + c] = (o >= 0.f) ? o : 0.01f * o;
}

extern "C" void kernel_launch(void* const* d_in, const int* in_sizes, int n_in,
                              void* d_out, int out_size, void* d_ws, size_t ws_size,
                              hipStream_t stream) {
  (void)n_in; (void)out_size; (void)ws_size;
  const float* score = (const float*)d_in[0];
  const float* nrepr = (const float*)d_in[1];
  const int*   eg0   = (const int*)d_in[2];
  const int*   src0  = (const int*)d_in[3];
  const int*   dst0  = (const int*)d_in[4];
  const float* rel0  = (const float*)d_in[5];
  const int*   eg1   = (const int*)d_in[6];
  const int*   src1  = (const int*)d_in[7];
  const int*   dst1  = (const int*)d_in[8];
  const float* rel1  = (const float*)d_in[9];
  const float* qemb  = (const float*)d_in[10];
  const float* remb  = (const float*)d_in[11];
  const float* Wq    = (const float*)d_in[12];
  const float* Wk    = (const float*)d_in[13];
  const float* Wlin  = (const float*)d_in[14];
  const float* blin  = (const float*)d_in[15];
  const int*   maxe  = (const int*)d_in[16];

  const int N_ = in_sizes[0];
  const int E_ = in_sizes[2];
  const int Q_ = in_sizes[10] / DD;

  char* wsc = (char*)d_ws;
  size_t off = 0;
  auto alloc = [&](size_t bytes) -> void* {
    void* p = wsc + off;
    off += (bytes + 255) & ~(size_t)255;
    return p;
  };
  double* M64  = (double*)alloc((size_t)DD4 * DD4 * 8);
  double* p64  = (double*)alloc((size_t)Q_ * 64 * 8);
  double* pD64 = (double*)alloc((size_t)Q_ * DD * 8);
  double* c64  = (double*)alloc((size_t)Q_ * 8);
  float*  p32  = (float*)alloc((size_t)Q_ * 64 * 4);
  float*  pD32 = (float*)alloc((size_t)Q_ * DD * 4);
  float*  c32  = (float*)alloc((size_t)Q_ * 4);
  double* lg1  = (double*)alloc((size_t)E_ * 8);
  float*  w1f  = (float*)alloc((size_t)E_ * 4);
  unsigned int* tkey = (unsigned int*)alloc((size_t)E_ * 4);
  float*  w1p  = (float*)alloc((size_t)E_ * 4);
  float*  lg0  = (float*)alloc((size_t)E_ * 4);
  float*  repr1 = (float*)alloc((size_t)N_ * DD * 4);
  float*  tvec = (float*)alloc((size_t)N_ * DD * 4);   // reused: node-pre, then CSR scratch
  float*  uvec = (float*)alloc((size_t)N_ * DD * 4);   // reused: then pk
  float*  vvec = (float*)alloc((size_t)N_ * DD * 4);
  // zero-initialized region (contiguous)
  size_t zstart = off;
  unsigned long long* mkey1 = (unsigned long long*)alloc((size_t)N_ * 8);
  double* s1   = (double*)alloc((size_t)N_ * 8);
  float*  agg  = (float*)alloc((size_t)N_ * DD * 4);
  unsigned int* mkey0 = (unsigned int*)alloc((size_t)N_ * 4);
  float*  s0   = (float*)alloc((size_t)N_ * 4);
  size_t zlen = off - zstart;

  // CSR scratch aliases tvec/uvec (dead after k_edge_logits<float>).
  // NOTE padding: offcsr needs N+1 ints — cursor must start past offcsr[N].
  int* cnt    = (int*)tvec;                         // [0, N)
  int* offcsr = (int*)tvec + N_;                    // [N, 2N+1)  (N+1 ints!)
  int* cursor = (int*)tvec + 2 * (size_t)N_ + 64;   // padded past offcsr[N]
  int* bsum   = (int*)tvec + 3 * (size_t)N_ + 128;  // nblk ints
  float2* pk  = (float2*)uvec;                      // E float2 = 4 MB (uvec is 12.8 MB)

  float* out_score = (float*)d_out;
  float* out_repr  = out_score + N_;

  hipMemsetAsync(wsc + zstart, 0, zlen, stream);
  hipMemsetAsync(d_out, 0, (size_t)N_ * 4, stream);

  k_precompute_M<<<(DD4 * DD4) / TPB, TPB, 0, stream>>>(Wq, Wk, M64);
  k_per_query<<<Q_, 64, 0, stream>>>(M64, qemb, remb, p64, pD64, c64, p32, pD32, c32);

  const int ngrid = (N_ + TPB - 1) / TPB;
  const int egrid = (E_ + TPB - 1) / TPB;

  // ---- layer 1 (f64 logits path, selection-critical) ----
  k_node_pre<double><<<ngrid, TPB, 0, stream>>>(M64, nrepr, tvec, uvec, vvec, N_);
  k_edge_logits<double><<<egrid, TPB, 0, stream>>>(M64, nrepr, rel1, src1, dst1, eg1,
                                                   tvec, uvec, vvec, p64, pD64, c64,
                                                   lg1, (void*)mkey1, E_);
  k_expsum64<<<egrid, TPB, 0, stream>>>(lg1, mkey1, src1, s1, E_);
  k_weights_target<<<egrid, TPB, 0, stream>>>(lg1, s1, src1, score, w1f, tkey, E_);
  k_topk<<<Q_, TKTPB, 0, stream>>>(tkey, w1f, eg1, maxe, w1p, E_);

  const int agrid = (int)(((size_t)E_ * 8 + TPB - 1) / TPB);
  k_apply1<<<agrid, TPB, 0, stream>>>(w1p, src1, dst1, nrepr, score, agg, out_score, E_);
  k_mix<<<(N_ * 8 + TPB - 1) / TPB, TPB, 0, stream>>>((const float4*)agg, (const float4*)nrepr,
                                                      (float4*)repr1, 0.8f, 0.2f, N_ * 8);

  // ---- layer 0 (f32) ----
  k_node_pre<float><<<ngrid, TPB, 0, stream>>>(M64, repr1, tvec, uvec, vvec, N_);
  k_edge_logits<float><<<egrid, TPB, 0, stream>>>(M64, repr1, rel0, src0, dst0, eg0,
                                                  tvec, uvec, vvec, p32, pD32, c32,
                                                  lg0, (void*)mkey0, E_);
  k_expsum32<<<egrid, TPB, 0, stream>>>(lg0, mkey0, src0, s0, E_);

  // ---- CSR build (tvec/uvec now dead) + gather + fused final ----
  hipMemsetAsync(cnt, 0, (size_t)N_ * 4, stream);
  k_hist<<<egrid, TPB, 0, stream>>>(dst0, cnt, E_);
  const int nblk = (N_ + SCHUNK - 1) / SCHUNK;
  k_scan1<<<nblk, TPB, 0, stream>>>(cnt, offcsr, bsum, N_);
  k_scan2<<<1, 64, 0, stream>>>(bsum, offcsr, nblk, N_, E_);
  k_scan3<<<ngrid, TPB, 0, stream>>>(offcsr, bsum, cursor, N_);
  k_scatter0<<<egrid, TPB, 0, stream>>>(lg0, s0, src0, dst0, cursor, pk, E_);
  k_gather_final<<<(N_ + 7) / 8, TPB, 0, stream>>>(pk, offcsr, repr1, Wlin, blin, out_repr, N_);
}

// Round 7
// 828.577 us; speedup vs baseline: 1.1164x; 1.1164x over previous
//
#include <hip/hip_runtime.h>
#include <math.h>

#define DD 32
#define DD4 128
#define TPB 256
#define LDSCAP 6144

// ---------- sortable key mappings ----------
__device__ __forceinline__ unsigned long long dsort_key(double x) {
  unsigned long long b = (unsigned long long)__double_as_longlong(x);
  return (b & 0x8000000000000000ull) ? ~b : (b | 0x8000000000000000ull);
}
__device__ __forceinline__ double dunsort_key(unsigned long long k) {
  unsigned long long b = (k & 0x8000000000000000ull) ? (k ^ 0x8000000000000000ull) : ~k;
  return __longlong_as_double((long long)b);
}
__device__ __forceinline__ unsigned int fsort_key(float x) {
  unsigned int b = __float_as_uint(x);
  return (b & 0x80000000u) ? ~b : (b | 0x80000000u);
}
__device__ __forceinline__ float funsort_key(unsigned int k) {
  unsigned int b = (k & 0x80000000u) ? (k ^ 0x80000000u) : ~k;
  return __uint_as_float(b);
}

// ---------- K1: M = Wq^T Wk (f64) ----------
__global__ __launch_bounds__(TPB) void k_precompute_M(
    const float* __restrict__ Wq, const float* __restrict__ Wk,
    double* __restrict__ M64) {
  int t = blockIdx.x * blockDim.x + threadIdx.x;  // 16384 threads
  int i = t >> 7, j = t & 127;
  double acc = 0.0;
  for (int k = 0; k < DD4; ++k)
    acc += (double)Wq[k * DD4 + i] * (double)Wk[k * DD4 + j];
  M64[i * DD4 + j] = acc;
}

// ---------- K2: per-query precompute p (64), pD (32), c (scalar) ----------
__global__ __launch_bounds__(64) void k_per_query(
    const double* __restrict__ M64,
    const float* __restrict__ qemb, const float* __restrict__ remb,
    double* __restrict__ p64, double* __restrict__ pD64, double* __restrict__ c64,
    float* __restrict__ p32, float* __restrict__ pD32, float* __restrict__ c32) {
  int q = blockIdx.x;
  int l = threadIdx.x;  // 64 threads = 1 wave
  __shared__ double qr[64];
  qr[l] = (l < DD) ? (double)qemb[q * DD + l] : (double)remb[q * DD + (l - DD)];
  __syncthreads();
  double a = 0.0;
  for (int j = 0; j < 64; ++j) a += M64[l * DD4 + 64 + j] * qr[j];
  double ct = 0.0;
  for (int j = 0; j < 64; ++j) ct += M64[(64 + j) * DD4 + l] * qr[j];
  if (l >= DD) a += ct;  // fold rel-part of z^T C x into p (x==y there)
  p64[q * 64 + l] = a;
  p32[q * 64 + l] = (float)a;
  if (l < DD) {
    pD64[q * DD + l] = ct;
    pD32[q * DD + l] = (float)ct;
  }
  double a3 = 0.0;
  for (int j = 0; j < 64; ++j) a3 += M64[(64 + l) * DD4 + 64 + j] * qr[j];
  a3 *= qr[l];
  for (int o = 32; o; o >>= 1) a3 += __shfl_xor(a3, o);
  if (l == 0) { c64[q] = a3; c32[q] = (float)a3; }
}

// ---------- K3: per-node precompute t = G11 h, u = G12^T h, v = G21 h ----------
template <typename T>
__global__ __launch_bounds__(TPB) void k_node_pre(
    const double* __restrict__ M64, const float* __restrict__ repr,
    float* __restrict__ t, float* __restrict__ u, float* __restrict__ v, int N_) {
  __shared__ T G11s[32 * 32];
  __shared__ T G12Ts[32 * 32];
  __shared__ T G21s[32 * 32];
  for (int i = threadIdx.x; i < 1024; i += TPB) {
    int r = i >> 5, c = i & 31;
    G11s[i]  = (T)M64[r * DD4 + c];
    G12Ts[i] = (T)M64[c * DD4 + 32 + r];
    G21s[i]  = (T)M64[(32 + r) * DD4 + c];
  }
  __syncthreads();
  int n = blockIdx.x * TPB + threadIdx.x;
  if (n >= N_) return;
  float h[32];
  const float4* h4 = (const float4*)repr + (size_t)n * 8;
#pragma unroll
  for (int j = 0; j < 8; ++j) {
    float4 x = h4[j];
    h[4 * j] = x.x; h[4 * j + 1] = x.y; h[4 * j + 2] = x.z; h[4 * j + 3] = x.w;
  }
  float4* t4 = (float4*)t + (size_t)n * 8;
  float4* u4 = (float4*)u + (size_t)n * 8;
  float4* v4 = (float4*)v + (size_t)n * 8;
#pragma unroll
  for (int ig = 0; ig < 8; ++ig) {
    float to[4], uo[4], vo[4];
#pragma unroll
    for (int ii = 0; ii < 4; ++ii) {
      const int i = ig * 4 + ii;
      T at = (T)0, au = (T)0, av = (T)0;
#pragma unroll
      for (int j = 0; j < 32; ++j) {
        T hj = (T)h[j];
        at += G11s[i * 32 + j] * hj;
        au += G12Ts[i * 32 + j] * hj;
        av += G21s[i * 32 + j] * hj;
      }
      to[ii] = (float)at; uo[ii] = (float)au; vo[ii] = (float)av;
    }
    t4[ig] = make_float4(to[0], to[1], to[2], to[3]);
    u4[ig] = make_float4(uo[0], uo[1], uo[2], uo[3]);
    v4[ig] = make_float4(vo[0], vo[1], vo[2], vo[3]);
  }
}

// ---------- K4: thread-per-edge logits ----------
template <typename T>
__global__ __launch_bounds__(TPB) void k_edge_logits(
    const double* __restrict__ M64,
    const float* __restrict__ repr, const float* __restrict__ rel,
    const int* __restrict__ src, const int* __restrict__ dst, const int* __restrict__ eg,
    const float* __restrict__ tvec, const float* __restrict__ uvec, const float* __restrict__ vvec,
    const T* __restrict__ pq, const T* __restrict__ pDq, const T* __restrict__ cq,
    T* __restrict__ logits, void* __restrict__ mkey, int E) {
  __shared__ T G22s[32 * 32];
  for (int i = threadIdx.x; i < 1024; i += TPB) {
    int r = i >> 5, c = i & 31;
    G22s[i] = (T)M64[(32 + r) * DD4 + 32 + c];
  }
  __syncthreads();
  const int e = blockIdx.x * TPB + threadIdx.x;
  if (e >= E) return;
  const int s = src[e], d = dst[e], q = eg[e];
  T acc = cq[q];
  {
    float hs[32], td[32];
    const float4* a4 = (const float4*)repr + (size_t)s * 8;
    const float4* b4 = (const float4*)tvec + (size_t)d * 8;
#pragma unroll
    for (int j = 0; j < 8; ++j) {
      float4 x = a4[j], y = b4[j];
      hs[4 * j] = x.x; hs[4 * j + 1] = x.y; hs[4 * j + 2] = x.z; hs[4 * j + 3] = x.w;
      td[4 * j] = y.x; td[4 * j + 1] = y.y; td[4 * j + 2] = y.z; td[4 * j + 3] = y.w;
    }
#pragma unroll
    for (int i = 0; i < 32; ++i)
      acc += (T)hs[i] * ((T)td[i] + pq[q * 64 + i]);
  }
  {
    float hd[32];
    const float4* a4 = (const float4*)repr + (size_t)d * 8;
#pragma unroll
    for (int j = 0; j < 8; ++j) {
      float4 x = a4[j];
      hd[4 * j] = x.x; hd[4 * j + 1] = x.y; hd[4 * j + 2] = x.z; hd[4 * j + 3] = x.w;
    }
#pragma unroll
    for (int i = 0; i < 32; ++i)
      acc += (T)hd[i] * pDq[q * DD + i];
  }
  float rl[32];
  {
    const float4* r4 = (const float4*)rel + (size_t)e * 8;
#pragma unroll
    for (int j = 0; j < 8; ++j) {
      float4 x = r4[j];
      rl[4 * j] = x.x; rl[4 * j + 1] = x.y; rl[4 * j + 2] = x.z; rl[4 * j + 3] = x.w;
    }
  }
  T rowv[32];
  {
    const float4* u4 = (const float4*)uvec + (size_t)s * 8;
    const float4* v4 = (const float4*)vvec + (size_t)d * 8;
#pragma unroll
    for (int j = 0; j < 8; ++j) {
      float4 x = u4[j], y = v4[j];
      rowv[4 * j + 0] = (T)(x.x + y.x) + pq[q * 64 + 32 + 4 * j + 0];
      rowv[4 * j + 1] = (T)(x.y + y.y) + pq[q * 64 + 32 + 4 * j + 1];
      rowv[4 * j + 2] = (T)(x.z + y.z) + pq[q * 64 + 32 + 4 * j + 2];
      rowv[4 * j + 3] = (T)(x.w + y.w) + pq[q * 64 + 32 + 4 * j + 3];
    }
  }
#pragma unroll 4
  for (int j = 0; j < 32; ++j) {
    const T rj = (T)rl[j];
#pragma unroll
    for (int i = 0; i < 32; ++i)
      rowv[i] += G22s[i * 32 + j] * rj;
  }
#pragma unroll
  for (int i = 0; i < 32; ++i) acc += (T)rl[i] * rowv[i];

  logits[e] = acc;
  if constexpr (sizeof(T) == 8) {
    atomicMax((unsigned long long*)mkey + s, dsort_key((double)acc));
  } else {
    atomicMax((unsigned int*)mkey + s, fsort_key((float)acc));
  }
}

// ---------- K5: ex = exp(l - m[src]); s[src] += ex (in-place) ----------
__global__ __launch_bounds__(TPB) void k_expsum64(
    double* __restrict__ io, const unsigned long long* __restrict__ mkey,
    const int* __restrict__ src, double* __restrict__ ssum, int E) {
  int e = blockIdx.x * blockDim.x + threadIdx.x;
  if (e >= E) return;
  int s = src[e];
  double ex = exp(io[e] - dunsort_key(mkey[s]));
  io[e] = ex;
  atomicAdd(&ssum[s], ex);
}
__global__ __launch_bounds__(TPB) void k_expsum32(
    float* __restrict__ io, const unsigned int* __restrict__ mkey,
    const int* __restrict__ src, float* __restrict__ ssum, int E) {
  int e = blockIdx.x * blockDim.x + threadIdx.x;
  if (e >= E) return;
  int s = src[e];
  float ex = expf(io[e] - funsort_key(mkey[s]));
  io[e] = ex;
  atomicAdd(&ssum[s], ex);
}

// ---------- K6: w1 = ex/s; target key = fsort(f32(w1) * score[src]) ----------
__global__ __launch_bounds__(TPB) void k_weights_target(
    const double* __restrict__ ex, const double* __restrict__ ssum,
    const int* __restrict__ src, const float* __restrict__ score,
    float* __restrict__ w1f, unsigned int* __restrict__ tkey, int E) {
  int e = blockIdx.x * blockDim.x + threadIdx.x;
  if (e >= E) return;
  int s = src[e];
  double w = ex[e] / ssum[s];
  float wf = (float)w;
  w1f[e] = wf;
  float tgt = wf * score[s];
  tkey[e] = fsort_key(tgt);
}

// ---------- K6b: qoff[v] = first edge index with eg >= v (eg sorted) ----------
__global__ __launch_bounds__(TPB) void k_qoff(
    const int* __restrict__ eg, int* __restrict__ qoff, int E, int Q) {
  int e = blockIdx.x * blockDim.x + threadIdx.x;
  if (e >= E) return;
  int cur = eg[e];
  int prev = (e == 0) ? -1 : eg[e - 1];
  for (int v = prev + 1; v <= cur; ++v) qoff[v] = e;
  if (e == E - 1) {
    for (int v = cur + 1; v <= Q; ++v) qoff[v] = E;
  }
}

// ---------- K7: per-query top-k via 4-pass radix select (LDS hist) ----------
__global__ __launch_bounds__(TPB) void k_topk(
    const unsigned int* __restrict__ tkey, const float* __restrict__ w1f,
    const int* __restrict__ qoff, const int* __restrict__ maxe,
    float* __restrict__ w1p, int E) {
  __shared__ unsigned int keys[LDSCAP];
  __shared__ int hist[256];
  __shared__ int sc[TPB];
  __shared__ unsigned int sh_prefix;
  __shared__ int sh_need;
  const int q = blockIdx.x;
  const int s = qoff[q], e2 = qoff[q + 1];
  const int n = e2 - s;
  const int K = maxe[0];
  if (n <= K) {
    for (int i = s + threadIdx.x; i < e2; i += TPB) w1p[i] = w1f[i];
    return;
  }
  const bool useLds = (n <= LDSCAP);
  if (useLds) {
    for (int i = threadIdx.x; i < n; i += TPB) keys[i] = tkey[s + i];
  }
  __syncthreads();
  unsigned int prefix = 0u;
  int need = K;
  for (int pass = 0; pass < 4; ++pass) {
    const int shift = 24 - 8 * pass;
    const unsigned int himask = (pass == 0) ? 0u : (0xFFFFFFFFu << (shift + 8));
    hist[threadIdx.x] = 0;                     // TPB==256
    __syncthreads();
    if (useLds) {
      for (int i = threadIdx.x; i < n; i += TPB) {
        unsigned int k = keys[i];
        if ((k & himask) == prefix) atomicAdd(&hist[(k >> shift) & 255], 1);
      }
    } else {
      for (int i = s + threadIdx.x; i < e2; i += TPB) {
        unsigned int k = tkey[i];
        if ((k & himask) == prefix) atomicAdd(&hist[(k >> shift) & 255], 1);
      }
    }
    __syncthreads();
    if (threadIdx.x == 0) {
      int cum = 0;
      for (int d = 255; d >= 0; --d) {
        int h = hist[d];
        if (cum + h >= need) {
          sh_need = need - cum;
          sh_prefix = prefix | ((unsigned int)d << shift);
          break;
        }
        cum += h;
      }
    }
    __syncthreads();
    prefix = sh_prefix;
    need = sh_need;
    __syncthreads();
  }
  const unsigned int kth = prefix;   // exact kth-largest key
  const int r = need;                // # of kth-valued ties to keep (index order)
  // blocked chunks -> index-ordered tie ranks via block scan
  const int C = (n + TPB - 1) / TPB;
  const int b0 = min(threadIdx.x * C, n);
  const int b1 = min(b0 + C, n);
  int myt = 0;
  for (int i = b0; i < b1; ++i) {
    unsigned int k = useLds ? keys[i] : tkey[s + i];
    myt += (k == kth) ? 1 : 0;
  }
  sc[threadIdx.x] = myt;
  __syncthreads();
  for (int o = 1; o < TPB; o <<= 1) {
    int x = (threadIdx.x >= o) ? sc[threadIdx.x - o] : 0;
    __syncthreads();
    sc[threadIdx.x] += x;
    __syncthreads();
  }
  int tiepre = sc[threadIdx.x] - myt;  // exclusive prefix of ties before my chunk
  for (int i = b0; i < b1; ++i) {
    unsigned int k = useLds ? keys[i] : tkey[s + i];
    float v = 0.f;
    if (k > kth) {
      v = w1f[s + i];
    } else if (k == kth) {
      if (tiepre < r) v = w1f[s + i];
      ++tiepre;
    }
    w1p[s + i] = v;
  }
}

// ---------- K8: layer-1 scatter: score + repr agg over kept edges (sparse) ----------
__global__ __launch_bounds__(TPB) void k_apply1(
    const float* __restrict__ w1p, const int* __restrict__ src, const int* __restrict__ dst,
    const float* __restrict__ repr0, const float* __restrict__ score,
    float* __restrict__ agg, float* __restrict__ score_out, int E) {
  int t = blockIdx.x * blockDim.x + threadIdx.x;
  int e = t >> 3, part = t & 7;
  if (e >= E) return;
  float w = w1p[e];
  if (w == 0.f) return;
  int sv = src[e], dv = dst[e];
  const float4 rv = ((const float4*)repr0)[sv * 8 + part];
  float* ap = agg + (size_t)dv * DD + part * 4;
  atomicAdd(ap + 0, w * rv.x);
  atomicAdd(ap + 1, w * rv.y);
  atomicAdd(ap + 2, w * rv.z);
  atomicAdd(ap + 3, w * rv.w);
  if (part == 0) atomicAdd(score_out + dv, w * score[sv]);
}

// ---------- K9: out = wa*a + wb*b ----------
__global__ __launch_bounds__(TPB) void k_mix(
    const float4* __restrict__ a, const float4* __restrict__ b,
    float4* __restrict__ out, float wa, float wb, int n4) {
  int i = blockIdx.x * blockDim.x + threadIdx.x;
  if (i >= n4) return;
  float4 x = a[i], y = b[i];
  out[i] = make_float4(wa * x.x + wb * y.x, wa * x.y + wb * y.y,
                       wa * x.z + wb * y.z, wa * x.w + wb * y.w);
}

// ---------- CSR build for layer-0 dst ----------
__global__ __launch_bounds__(TPB) void k_hist(
    const int* __restrict__ dst, int* __restrict__ cnt, int E) {
  int e = blockIdx.x * blockDim.x + threadIdx.x;
  if (e >= E) return;
  atomicAdd(&cnt[dst[e]], 1);
}

#define SCHUNK 1024
__global__ __launch_bounds__(TPB) void k_scan1(
    const int* __restrict__ cnt, int* __restrict__ off, int* __restrict__ bsum, int N_) {
  __shared__ int sd[TPB];
  const int b = blockIdx.x, t = threadIdx.x;
  const int base = b * SCHUNK + t * 4;
  int v[4];
  int s4 = 0;
#pragma unroll
  for (int k = 0; k < 4; ++k) {
    v[k] = (base + k < N_) ? cnt[base + k] : 0;
    s4 += v[k];
  }
  sd[t] = s4;
  __syncthreads();
  for (int o = 1; o < TPB; o <<= 1) {
    int x = (t >= o) ? sd[t - o] : 0;
    __syncthreads();
    sd[t] += x;
    __syncthreads();
  }
  int excl = sd[t] - s4;
  if (t == TPB - 1) bsum[b] = sd[t];
  int run = excl;
#pragma unroll
  for (int k = 0; k < 4; ++k) {
    if (base + k < N_) { off[base + k] = run; run += v[k]; }
  }
}

__global__ void k_scan2(int* __restrict__ bsum, int* __restrict__ off, int nblk, int N_, int E) {
  if (threadIdx.x != 0 || blockIdx.x != 0) return;
  int run = 0;
  for (int i = 0; i < nblk; ++i) { int tmp = bsum[i]; bsum[i] = run; run += tmp; }
  off[N_] = E;
}

__global__ __launch_bounds__(TPB) void k_scan3(
    int* __restrict__ off, const int* __restrict__ bsum, int* __restrict__ cursor, int N_) {
  int i = blockIdx.x * blockDim.x + threadIdx.x;
  if (i >= N_) return;
  int v = off[i] + bsum[i >> 10];
  off[i] = v;
  cursor[i] = v;
}

// ---------- K12a: scatter packed {w, src} into dst-CSR order ----------
__global__ __launch_bounds__(TPB) void k_scatter0(
    const float* __restrict__ ex, const float* __restrict__ ssum,
    const int* __restrict__ src, const int* __restrict__ dst,
    int* __restrict__ cursor, float2* __restrict__ pk, int E) {
  int e = blockIdx.x * blockDim.x + threadIdx.x;
  if (e >= E) return;
  int s = src[e];
  float w = ex[e] / ssum[s];
  int pos = atomicAdd(&cursor[dst[e]], 1);
  pk[pos] = make_float2(w, __int_as_float(s));
}

// ---------- K12b: gather per dst node + fused mix + Linear + LeakyReLU ----------
__global__ __launch_bounds__(TPB) void k_gather_final(
    const float2* __restrict__ pk, const int* __restrict__ off,
    const float* __restrict__ repr1,
    const float* __restrict__ Wlin, const float* __restrict__ blin,
    float* __restrict__ out_repr, int N_) {
  __shared__ float WsT[DD * DD];   // WsT[j*32+i] = Wlin[i*32+j]
  __shared__ float bs[DD];
  for (int i = threadIdx.x; i < DD * DD; i += TPB) {
    int r = i >> 5, c = i & 31;
    WsT[c * DD + r] = Wlin[i];
  }
  if (threadIdx.x < DD) bs[threadIdx.x] = blin[threadIdx.x];
  __syncthreads();
  const int n = blockIdx.x * 8 + (threadIdx.x >> 5);  // node
  const int c = threadIdx.x & 31;                     // component
  if (n >= N_) return;
  float acc = 0.f;
  const int j1 = off[n + 1];
  for (int j = off[n]; j < j1; ++j) {
    float2 p = pk[j];
    int s = __float_as_int(p.y);
    acc += p.x * repr1[(size_t)s * DD + c];
  }
  float mix = 0.8f * acc + 0.2f * repr1[(size_t)n * DD + c];
  float o = bs[c];
#pragma unroll 8
  for (int j = 0; j < DD; ++j) {
    float mj = __shfl(mix, j, 32);
    o += WsT[j * DD + c] * mj;
  }
  out_repr[(size_t)n * DD + c] = (o >= 0.f) ? o : 0.01f * o;
}

extern "C" void kernel_launch(void* const* d_in, const int* in_sizes, int n_in,
                              void* d_out, int out_size, void* d_ws, size_t ws_size,
                              hipStream_t stream) {
  (void)n_in; (void)out_size; (void)ws_size;
  const float* score = (const float*)d_in[0];
  const float* nrepr = (const float*)d_in[1];
  const int*   eg0   = (const int*)d_in[2];
  const int*   src0  = (const int*)d_in[3];
  const int*   dst0  = (const int*)d_in[4];
  const float* rel0  = (const float*)d_in[5];
  const int*   eg1   = (const int*)d_in[6];
  const int*   src1  = (const int*)d_in[7];
  const int*   dst1  = (const int*)d_in[8];
  const float* rel1  = (const float*)d_in[9];
  const float* qemb  = (const float*)d_in[10];
  const float* remb  = (const float*)d_in[11];
  const float* Wq    = (const float*)d_in[12];
  const float* Wk    = (const float*)d_in[13];
  const float* Wlin  = (const float*)d_in[14];
  const float* blin  = (const float*)d_in[15];
  const int*   maxe  = (const int*)d_in[16];

  const int N_ = in_sizes[0];
  const int E_ = in_sizes[2];
  const int Q_ = in_sizes[10] / DD;

  char* wsc = (char*)d_ws;
  size_t off = 0;
  auto alloc = [&](size_t bytes) -> void* {
    void* p = wsc + off;
    off += (bytes + 255) & ~(size_t)255;
    return p;
  };
  double* M64  = (double*)alloc((size_t)DD4 * DD4 * 8);
  double* p64  = (double*)alloc((size_t)Q_ * 64 * 8);
  double* pD64 = (double*)alloc((size_t)Q_ * DD * 8);
  double* c64  = (double*)alloc((size_t)Q_ * 8);
  float*  p32  = (float*)alloc((size_t)Q_ * 64 * 4);
  float*  pD32 = (float*)alloc((size_t)Q_ * DD * 4);
  float*  c32  = (float*)alloc((size_t)Q_ * 4);
  int*    qoff = (int*)alloc((size_t)(Q_ + 2) * 4);
  double* lg1  = (double*)alloc((size_t)E_ * 8);
  float*  w1f  = (float*)alloc((size_t)E_ * 4);
  unsigned int* tkey = (unsigned int*)alloc((size_t)E_ * 4);
  float*  w1p  = (float*)alloc((size_t)E_ * 4);
  float*  lg0  = (float*)alloc((size_t)E_ * 4);
  float*  repr1 = (float*)alloc((size_t)N_ * DD * 4);
  float*  tvec = (float*)alloc((size_t)N_ * DD * 4);   // reused: node-pre, then CSR scratch
  float*  uvec = (float*)alloc((size_t)N_ * DD * 4);   // reused: then pk
  float*  vvec = (float*)alloc((size_t)N_ * DD * 4);
  // zero-initialized region (contiguous)
  size_t zstart = off;
  unsigned long long* mkey1 = (unsigned long long*)alloc((size_t)N_ * 8);
  double* s1   = (double*)alloc((size_t)N_ * 8);
  float*  agg  = (float*)alloc((size_t)N_ * DD * 4);
  unsigned int* mkey0 = (unsigned int*)alloc((size_t)N_ * 4);
  float*  s0   = (float*)alloc((size_t)N_ * 4);
  size_t zlen = off - zstart;

  // CSR scratch aliases tvec/uvec (dead after k_edge_logits<float>).
  // NOTE padding: offcsr needs N+1 ints — cursor must start past offcsr[N].
  int* cnt    = (int*)tvec;                         // [0, N)
  int* offcsr = (int*)tvec + N_;                    // [N, 2N+1)  (N+1 ints!)
  int* cursor = (int*)tvec + 2 * (size_t)N_ + 64;   // padded past offcsr[N]
  int* bsum   = (int*)tvec + 3 * (size_t)N_ + 128;  // nblk ints
  float2* pk  = (float2*)uvec;                      // E float2 = 4 MB (uvec is 12.8 MB)

  float* out_score = (float*)d_out;
  float* out_repr  = out_score + N_;

  hipMemsetAsync(wsc + zstart, 0, zlen, stream);
  hipMemsetAsync(d_out, 0, (size_t)N_ * 4, stream);

  k_precompute_M<<<(DD4 * DD4) / TPB, TPB, 0, stream>>>(Wq, Wk, M64);
  k_per_query<<<Q_, 64, 0, stream>>>(M64, qemb, remb, p64, pD64, c64, p32, pD32, c32);

  const int ngrid = (N_ + TPB - 1) / TPB;
  const int egrid = (E_ + TPB - 1) / TPB;

  // ---- layer 1 (f64 logits path, selection-critical) ----
  k_node_pre<double><<<ngrid, TPB, 0, stream>>>(M64, nrepr, tvec, uvec, vvec, N_);
  k_edge_logits<double><<<egrid, TPB, 0, stream>>>(M64, nrepr, rel1, src1, dst1, eg1,
                                                   tvec, uvec, vvec, p64, pD64, c64,
                                                   lg1, (void*)mkey1, E_);
  k_expsum64<<<egrid, TPB, 0, stream>>>(lg1, mkey1, src1, s1, E_);
  k_weights_target<<<egrid, TPB, 0, stream>>>(lg1, s1, src1, score, w1f, tkey, E_);
  k_qoff<<<egrid, TPB, 0, stream>>>(eg1, qoff, E_, Q_);
  k_topk<<<Q_, TPB, 0, stream>>>(tkey, w1f, qoff, maxe, w1p, E_);

  const int agrid = (int)(((size_t)E_ * 8 + TPB - 1) / TPB);
  k_apply1<<<agrid, TPB, 0, stream>>>(w1p, src1, dst1, nrepr, score, agg, out_score, E_);
  k_mix<<<(N_ * 8 + TPB - 1) / TPB, TPB, 0, stream>>>((const float4*)agg, (const float4*)nrepr,
                                                      (float4*)repr1, 0.8f, 0.2f, N_ * 8);

  // ---- layer 0 (f32) ----
  k_node_pre<float><<<ngrid, TPB, 0, stream>>>(M64, repr1, tvec, uvec, vvec, N_);
  k_edge_logits<float><<<egrid, TPB, 0, stream>>>(M64, repr1, rel0, src0, dst0, eg0,
                                                  tvec, uvec, vvec, p32, pD32, c32,
                                                  lg0, (void*)mkey0, E_);
  k_expsum32<<<egrid, TPB, 0, stream>>>(lg0, mkey0, src0, s0, E_);

  // ---- CSR build (tvec/uvec now dead) + gather + fused final ----
  hipMemsetAsync(cnt, 0, (size_t)N_ * 4, stream);
  k_hist<<<egrid, TPB, 0, stream>>>(dst0, cnt, E_);
  const int nblk = (N_ + SCHUNK - 1) / SCHUNK;
  k_scan1<<<nblk, TPB, 0, stream>>>(cnt, offcsr, bsum, N_);
  k_scan2<<<1, 64, 0, stream>>>(bsum, offcsr, nblk, N_, E_);
  k_scan3<<<ngrid, TPB, 0, stream>>>(offcsr, bsum, cursor, N_);
  k_scatter0<<<egrid, TPB, 0, stream>>>(lg0, s0, src0, dst0, cursor, pk, E_);
  k_gather_final<<<(N_ + 7) / 8, TPB, 0, stream>>>(pk, offcsr, repr1, Wlin, blin, out_repr, N_);
}